// Round 6
// baseline (2793.446 us; speedup 1.0000x reference)
//
#include <hip/hip_runtime.h>

// Bahdanau attention: B=32, T=512, S=1024, H=512, fp32.
// out = context [B,T,H] ++ attn_last [B,S]
// ws  = Q [B,T,H] ++ E4 [B,H/32,S,32]; Q = e^{2*Wsq}, E = e^{2*Whe} (clamped
// exp2 in matmul epilogues). Score trick: softmax shift-invariance =>
// score' = -2 * sum_h v_h / (1 + Q*E); h-quads combined by a reciprocal tree
// (14 VALU + 1 rcp per 4 elements). Phase A is flat-pair scheduled: P=4*NS*64
// pairs, always a multiple of 256 -> zero wave-quantization waste; t is
// wave-uniform -> Q-row/v reads become scalar (s_load) off the VALU pipe.

constexpr int B = 32, T = 512, S = 1024, H = 512;
constexpr int TT = 4;  // timesteps per attn block
constexpr float C2LOG2E = 2.88539008177792681f;  // 2*log2(e)

typedef float vf4 __attribute__((ext_vector_type(4)));

#define DEVI __device__ __forceinline__

DEVI vf4 exp2clampv(vf4 x) {
  vf4 r;
#pragma unroll
  for (int i = 0; i < 4; ++i)
    r[i] = __builtin_amdgcn_exp2f(fminf(fmaxf(x[i], -15.f), 15.f));
  return r;
}

// C = exp2(clamp(scale * A[M][512] * W[512][512]^T)). TRANS=false: C[m][o].
// TRANS=true: C as [b][o/32][s][32], m = b*S + s; fully-masked s-tiles skipped.
template <bool TRANS>
__global__ __launch_bounds__(256)
void matmul_nt_kernel(const float* __restrict__ A, const float* __restrict__ W,
                      float* __restrict__ Cout, float scale, const int* __restrict__ lens) {
  constexpr int K = H, N = H, BM = 64, BN = 64, BK = 16;
  __shared__ __align__(16) float As[BK][BM + 4];
  __shared__ __align__(16) float Bs[BK][BN + 4];
  const int nbx = N / BN;  // 8
  const int bx = blockIdx.x % nbx, by = blockIdx.x / nbx;
  const int row0 = by * BM, col0 = bx * BN;
  if (TRANS) {  // rows row0..row0+63 are one batch; skip if fully masked
    if ((row0 % S) >= lens[row0 / S]) return;
  }
  const int tid = threadIdx.x;
  const int tx = tid & 15, ty = tid >> 4;
  const int lr = tid >> 2, lk = (tid & 3) * 4;
  float acc[4][4] = {};
  for (int k0 = 0; k0 < K; k0 += BK) {
    float4 av = *(const float4*)&A[(size_t)(row0 + lr) * K + k0 + lk];
    float4 wv = *(const float4*)&W[(size_t)(col0 + lr) * K + k0 + lk];
    __syncthreads();
    As[lk + 0][lr] = av.x; As[lk + 1][lr] = av.y; As[lk + 2][lr] = av.z; As[lk + 3][lr] = av.w;
    Bs[lk + 0][lr] = wv.x; Bs[lk + 1][lr] = wv.y; Bs[lk + 2][lr] = wv.z; Bs[lk + 3][lr] = wv.w;
    __syncthreads();
#pragma unroll
    for (int k = 0; k < BK; ++k) {
      float4 a4 = *(const float4*)&As[k][ty * 4];
      float4 w4 = *(const float4*)&Bs[k][tx * 4];
      float a[4] = {a4.x, a4.y, a4.z, a4.w};
      float w[4] = {w4.x, w4.y, w4.z, w4.w};
#pragma unroll
      for (int i = 0; i < 4; ++i)
#pragma unroll
        for (int j = 0; j < 4; ++j) acc[i][j] = __builtin_fmaf(a[i], w[j], acc[i][j]);
    }
  }
  if (!TRANS) {
#pragma unroll
    for (int i = 0; i < 4; ++i) {
      vf4 o = {acc[i][0] * scale, acc[i][1] * scale, acc[i][2] * scale, acc[i][3] * scale};
      *(vf4*)&Cout[(size_t)(row0 + ty * 4 + i) * N + col0 + tx * 4] = exp2clampv(o);
    }
  } else {
    const int b = row0 / S;
    const int sl = (row0 % S) + ty * 4;
    const int h0 = col0 + tx * 4;  // h0..h0+3 stay within one 32-group
    float* base = Cout + (size_t)b * (H * S) + (size_t)(h0 >> 5) * (S * 32) + (h0 & 31);
#pragma unroll
    for (int i = 0; i < 4; ++i) {
      vf4 o = {acc[i][0] * scale, acc[i][1] * scale, acc[i][2] * scale, acc[i][3] * scale};
      *(vf4*)&base[(size_t)(sl + i) * 32] = exp2clampv(o);
    }
  }
}

// acc += sum_{i<4} vv[i] / (1 + q[i]*e[i])  via single-rcp reciprocal tree.
DEVI void quad(float& acc, vf4 q, vf4 vv, vf4 e) {
  float a0 = __builtin_fmaf(q[0], e[0], 1.0f);
  float a1 = __builtin_fmaf(q[1], e[1], 1.0f);
  float a2 = __builtin_fmaf(q[2], e[2], 1.0f);
  float a3 = __builtin_fmaf(q[3], e[3], 1.0f);
  float d01 = a0 * a1, d23 = a2 * a3;
  float n01 = __builtin_fmaf(vv[1], a0, vv[0] * a1);
  float n23 = __builtin_fmaf(vv[3], a2, vv[2] * a3);
  float d = d01 * d23;
  float n = __builtin_fmaf(n23, d01, n01 * d23);
  acc = __builtin_fmaf(n, __builtin_amdgcn_rcpf(d), acc);
}

// Fused: scores -> masked softmax -> context. One block = (b, 4 timesteps).
__global__ __launch_bounds__(256, 5)
void attn_fused_kernel(const float* __restrict__ wsq, const float* __restrict__ e4,
                       const float* __restrict__ enc, const float* __restrict__ v,
                       const int* __restrict__ lens, float* __restrict__ out) {
  __shared__ __align__(16) float s_sc[TT][S];  // 16 KB: scores, then p in place
  __shared__ float s_rs[TT];
  __shared__ long long s_w[32];
  __shared__ int s_bsel;

  const int tid = threadIdx.x;
  const int xcd = blockIdx.x & 7;     // dispatch round-robin heuristic
  const int j = blockIdx.x >> 3;      // 0..511
  const int slot = j >> 7;            // 0..3: which of this XCD's 4 batches
  const int tt = j & 127;             // 0..127 t-tile within batch

  // Runtime snake load-balance: rank batches by len (desc), XCD x gets ranks
  // {x, 15-x, 16+x, 31-x} -> balanced work, batch-major locality.
  if (tid < 32) s_w[tid] = ((long long)lens[tid] << 8) + tid;  // unique key
  __syncthreads();
  if (tid < 32) {
    long long wb = s_w[tid];
    int rank = 0;
#pragma unroll
    for (int b2 = 0; b2 < 32; ++b2) rank += (s_w[b2] > wb);
    int myrank = slot * 8 + ((slot & 1) ? (7 - xcd) : xcd);
    if (rank == myrank) s_bsel = tid;
  }
  __syncthreads();
  const int b = __builtin_amdgcn_readfirstlane(s_bsel);
  const int len = lens[b];

  // ---- Phase A: flat (t,s) pairs, P = 4*NS64 ≡ 0 mod 256 -> NS full rounds.
  // t wave-uniform -> Q-row/v via scalar loads; E double-buffered 8-groups. ----
  {
    const int NS64 = ((len + 63) >> 6) << 6;
    const int P = 4 * NS64;
    const float* e4b = e4 + (size_t)b * (H * S);
    const float* qbase = wsq + ((size_t)b * T + (size_t)tt * TT) * H;
    for (int r0 = 0; r0 < P; r0 += 256) {
      const int pair = r0 + tid;
      const int t = (pair >= NS64) + (pair >= 2 * NS64) + (pair >= 3 * NS64);
      const int s = pair - t * NS64;
      const float* qrow = qbase + (size_t)__builtin_amdgcn_readfirstlane(t) * H;
      const float* ep = e4b + (size_t)s * 32;
      float acc = 0.f;
      vf4 Ea[8], Eb[8];
#pragma unroll
      for (int u = 0; u < 8; ++u) Ea[u] = *(const vf4*)(ep + u * 4);
      for (int g = 0; g < 16; g += 2) {
        const float* ep1 = ep + (size_t)(g + 1) * (S * 32);
#pragma unroll
        for (int u = 0; u < 8; ++u) Eb[u] = *(const vf4*)(ep1 + u * 4);
#pragma unroll
        for (int u = 0; u < 8; ++u) {
          const int h = g * 32 + u * 4;
          quad(acc, *(const vf4*)(qrow + h), *(const vf4*)(v + h), Ea[u]);
        }
        if (g + 2 < 16) {
          const float* ep2 = ep + (size_t)(g + 2) * (S * 32);
#pragma unroll
          for (int u = 0; u < 8; ++u) Ea[u] = *(const vf4*)(ep2 + u * 4);
        }
#pragma unroll
        for (int u = 0; u < 8; ++u) {
          const int h = (g + 1) * 32 + u * 4;
          quad(acc, *(const vf4*)(qrow + h), *(const vf4*)(v + h), Eb[u]);
        }
      }
      s_sc[t][s] = -2.0f * acc;
    }
  }
  __syncthreads();

  // ---- Phase B: masked softmax; wave w handles row w ----
  {
    const int tr = tid >> 6, lane = tid & 63;
    float vals[S / 64], ps[S / 64];
    float m = -3.0e38f;
#pragma unroll
    for (int i = 0; i < S / 64; ++i) {
      int s = lane + 64 * i;
      vals[i] = s_sc[tr][s];
      if (s < len) m = fmaxf(m, vals[i]);
    }
#pragma unroll
    for (int o = 1; o < 64; o <<= 1) m = fmaxf(m, __shfl_xor(m, o, 64));
    float sum = 0.f;
#pragma unroll
    for (int i = 0; i < S / 64; ++i) {
      int s = lane + 64 * i;
      float p = (s < len) ? __builtin_amdgcn_exp2f((vals[i] - m) * 1.44269504088896341f) : 0.f;
      ps[i] = p;
      sum += p;
    }
#pragma unroll
    for (int o = 1; o < 64; o <<= 1) sum += __shfl_xor(sum, o, 64);
    float rs = 1.0f / sum;
#pragma unroll
    for (int i = 0; i < S / 64; ++i) s_sc[tr][lane + 64 * i] = ps[i];
    if (lane == 0) s_rs[tr] = rs;
    if (tt == T / TT - 1 && tr == TT - 1) {  // last timestep: attention weights
#pragma unroll
      for (int i = 0; i < S / 64; ++i)
        out[(size_t)B * T * H + (size_t)b * S + lane + 64 * i] = ps[i] * rs;
    }
  }
  __syncthreads();

  // ---- Phase C: ctx[t][h] = sum_{s<len} p[t][s] * enc[b][s][h]; wave = t ----
  {
    const int tg = tid >> 6, lane = tid & 63;
    const int h0 = lane * 4, h1 = 256 + lane * 4;
    float acc[8] = {};
    const float* encb = enc + (size_t)b * S * H;
    const int len4 = (len + 3) & ~3;  // p == 0 beyond len, safe to over-read
    for (int s0 = 0; s0 < len4; s0 += 4) {
      vf4 p4 = *(const vf4*)&s_sc[tg][s0];
#pragma unroll
      for (int k = 0; k < 4; ++k) {
        const float* er = encb + (size_t)(s0 + k) * H;
        float4 e0 = *(const float4*)(er + h0);
        float4 e1 = *(const float4*)(er + h1);
        float ev[8] = {e0.x, e0.y, e0.z, e0.w, e1.x, e1.y, e1.z, e1.w};
#pragma unroll
        for (int q = 0; q < 8; ++q) acc[q] = __builtin_fmaf(p4[k], ev[q], acc[q]);
      }
    }
    const float rs = s_rs[tg];
    const size_t base = ((size_t)b * T + tt * TT + tg) * H;
    float4 o;
    o = make_float4(acc[0] * rs, acc[1] * rs, acc[2] * rs, acc[3] * rs);
    *(float4*)&out[base + h0] = o;
    o = make_float4(acc[4] * rs, acc[5] * rs, acc[6] * rs, acc[7] * rs);
    *(float4*)&out[base + h1] = o;
  }
}

extern "C" void kernel_launch(void* const* d_in, const int* in_sizes, int n_in,
                              void* d_out, int out_size, void* d_ws, size_t ws_size,
                              hipStream_t stream) {
  const float* query = (const float*)d_in[0];  // [B,T,H]
  const float* enc   = (const float*)d_in[1];  // [B,S,H]
  const int*   lens  = (const int*)d_in[2];    // [B]
  const float* Ws    = (const float*)d_in[3];  // [H,H]
  const float* Wh    = (const float*)d_in[4];  // [H,H]
  const float* v     = (const float*)d_in[5];  // [H]
  float* out = (float*)d_out;
  float* wsq = (float*)d_ws;                   // [B,T,H] = Q
  float* e4  = wsq + (size_t)B * T * H;        // [B,H/32,S,32] = E

  matmul_nt_kernel<false><<<dim3((B * T / 64) * 8), 256, 0, stream>>>(query, Ws, wsq, C2LOG2E, nullptr);
  matmul_nt_kernel<true><<<dim3((B * S / 64) * 8), 256, 0, stream>>>(enc, Wh, e4, C2LOG2E, lens);
  attn_fused_kernel<<<dim3(B * (T / TT)), 256, 0, stream>>>(wsq, e4, enc, v, lens, out);
}

// Round 7
// 1021.342 us; speedup vs baseline: 2.7351x; 2.7351x over previous
//
#include <hip/hip_runtime.h>

// Bahdanau attention: B=32, T=512, S=1024, H=512, fp32.
// out = context [B,T,H] ++ attn_last [B,S]
// ws  = Q [B,T,H] ++ E8 [B,H/8,S,8]; Q = e^{2*Wsq}, E = e^{2*Whe} (clamped
// exp2 in matmul epilogues). Softmax shift-invariance => score' =
// sum_h (-2 v_h) / (1 + Q*E). Per 8 h-elems: two 4-elem reciprocal trees run
// in the two lanes of packed-fp32 (v_pk_*_f32) float2 ops -> 13 pk + 3 scalar
// + 1 rcp. Thread owns one s for 4 t (4x E reuse in regs); named-var 2-plane
// pipeline (NO register arrays -> no scratch, cf. round-6 spill regression).

constexpr int B = 32, T = 512, S = 1024, H = 512;
constexpr int TT = 4;  // timesteps per attn block
constexpr float C2LOG2E = 2.88539008177792681f;  // 2*log2(e)

typedef float vf4 __attribute__((ext_vector_type(4)));
typedef float f2 __attribute__((ext_vector_type(2)));

#define DEVI __device__ __forceinline__

DEVI vf4 exp2clampv(vf4 x) {
  vf4 r;
#pragma unroll
  for (int i = 0; i < 4; ++i)
    r[i] = __builtin_amdgcn_exp2f(fminf(fmaxf(x[i], -15.f), 15.f));
  return r;
}

// C = exp2(clamp(scale * A[M][512] * W[512][512]^T)). TRANS=false: C[m][o].
// TRANS=true: C as [b][o/8][s][8], m = b*S + s; fully-masked s-tiles skipped.
template <bool TRANS>
__global__ __launch_bounds__(256)
void matmul_nt_kernel(const float* __restrict__ A, const float* __restrict__ W,
                      float* __restrict__ Cout, float scale, const int* __restrict__ lens) {
  constexpr int K = H, N = H, BM = 64, BN = 64, BK = 16;
  __shared__ __align__(16) float As[BK][BM + 4];
  __shared__ __align__(16) float Bs[BK][BN + 4];
  const int nbx = N / BN;  // 8
  const int bx = blockIdx.x % nbx, by = blockIdx.x / nbx;
  const int row0 = by * BM, col0 = bx * BN;
  if (TRANS) {  // rows row0..row0+63 are one batch; skip if fully masked
    if ((row0 % S) >= lens[row0 / S]) return;
  }
  const int tid = threadIdx.x;
  const int tx = tid & 15, ty = tid >> 4;
  const int lr = tid >> 2, lk = (tid & 3) * 4;
  float acc[4][4] = {};
  for (int k0 = 0; k0 < K; k0 += BK) {
    float4 av = *(const float4*)&A[(size_t)(row0 + lr) * K + k0 + lk];
    float4 wv = *(const float4*)&W[(size_t)(col0 + lr) * K + k0 + lk];
    __syncthreads();
    As[lk + 0][lr] = av.x; As[lk + 1][lr] = av.y; As[lk + 2][lr] = av.z; As[lk + 3][lr] = av.w;
    Bs[lk + 0][lr] = wv.x; Bs[lk + 1][lr] = wv.y; Bs[lk + 2][lr] = wv.z; Bs[lk + 3][lr] = wv.w;
    __syncthreads();
#pragma unroll
    for (int k = 0; k < BK; ++k) {
      float4 a4 = *(const float4*)&As[k][ty * 4];
      float4 w4 = *(const float4*)&Bs[k][tx * 4];
      float a[4] = {a4.x, a4.y, a4.z, a4.w};
      float w[4] = {w4.x, w4.y, w4.z, w4.w};
#pragma unroll
      for (int i = 0; i < 4; ++i)
#pragma unroll
        for (int j = 0; j < 4; ++j) acc[i][j] = __builtin_fmaf(a[i], w[j], acc[i][j]);
    }
  }
  if (!TRANS) {
#pragma unroll
    for (int i = 0; i < 4; ++i) {
      vf4 o = {acc[i][0] * scale, acc[i][1] * scale, acc[i][2] * scale, acc[i][3] * scale};
      *(vf4*)&Cout[(size_t)(row0 + ty * 4 + i) * N + col0 + tx * 4] = exp2clampv(o);
    }
  } else {
    const int b = row0 / S;
    const int sl = (row0 % S) + ty * 4;
    const int h0 = col0 + tx * 4;  // multiple of 4; h0&7 in {0,4}
    float* base = Cout + (size_t)b * (H * S) + (size_t)(h0 >> 3) * (S * 8) + (h0 & 7);
#pragma unroll
    for (int i = 0; i < 4; ++i) {
      vf4 o = {acc[i][0] * scale, acc[i][1] * scale, acc[i][2] * scale, acc[i][3] * scale};
      *(vf4*)&base[(size_t)(sl + i) * 8] = exp2clampv(o);
    }
  }
}

DEVI f2 lo2(vf4 x) { f2 r = {x[0], x[1]}; return r; }
DEVI f2 hi2(vf4 x) { f2 r = {x[2], x[3]}; return r; }

// acc += sum over 8 h-elems of vv/(1+q*e): two 4-elem reciprocal trees in the
// two packed-fp32 lanes (pairs {h2j,h2j+1}), combined with one rcp.
DEVI void plane8(float& acc, const float* qp, const float* vp, vf4 elo, vf4 ehi) {
  const f2 one = {1.0f, 1.0f};
  vf4 qlo = *(const vf4*)(qp);
  vf4 qhi = *(const vf4*)(qp + 4);
  vf4 vlo = *(const vf4*)(vp);
  vf4 vhi = *(const vf4*)(vp + 4);
  f2 a0 = __builtin_elementwise_fma(lo2(qlo), lo2(elo), one);
  f2 a1 = __builtin_elementwise_fma(hi2(qlo), hi2(elo), one);
  f2 a2 = __builtin_elementwise_fma(lo2(qhi), lo2(ehi), one);
  f2 a3 = __builtin_elementwise_fma(hi2(qhi), hi2(ehi), one);
  f2 d01 = a0 * a1, d23 = a2 * a3;
  f2 n01 = __builtin_elementwise_fma(hi2(vlo), a0, lo2(vlo) * a1);
  f2 n23 = __builtin_elementwise_fma(hi2(vhi), a2, lo2(vhi) * a3);
  f2 d2 = d01 * d23;
  f2 n2 = __builtin_elementwise_fma(n23, d01, n01 * d23);
  float D = d2[0] * d2[1];
  float N = __builtin_fmaf(n2[0], d2[1], n2[1] * d2[0]);
  acc = __builtin_fmaf(N, __builtin_amdgcn_rcpf(D), acc);
}

// Fused: scores -> masked softmax -> context. One block = (b, 4 timesteps).
__global__ __launch_bounds__(256, 5)
void attn_fused_kernel(const float* __restrict__ wsq, const float* __restrict__ e8,
                       const float* __restrict__ enc, const float* __restrict__ v,
                       const int* __restrict__ lens, float* __restrict__ out) {
  __shared__ __align__(16) float s_wsq[TT][H];  // 8 KB : Q rows
  __shared__ __align__(16) float s_v[H];        // 2 KB : -2*v
  __shared__ __align__(16) float s_sc[TT][S];   // 16 KB: scores, then p in place
  __shared__ float s_rs[TT];
  __shared__ long long s_w[32];
  __shared__ int s_bsel;

  const int tid = threadIdx.x;
  const int xcd = blockIdx.x & 7;     // dispatch round-robin heuristic
  const int j = blockIdx.x >> 3;      // 0..511
  const int slot = j >> 7;            // 0..3: which of this XCD's 4 batches
  const int tt = j & 127;             // 0..127 t-tile within batch

  // Runtime snake load-balance: rank batches by len (desc), XCD x gets ranks
  // {x, 15-x, 16+x, 31-x} -> balanced work, batch-major locality.
  if (tid < 32) s_w[tid] = ((long long)lens[tid] << 8) + tid;  // unique key
  __syncthreads();
  if (tid < 32) {
    long long wb = s_w[tid];
    int rank = 0;
#pragma unroll
    for (int b2 = 0; b2 < 32; ++b2) rank += (s_w[b2] > wb);
    int myrank = slot * 8 + ((slot & 1) ? (7 - xcd) : xcd);
    if (rank == myrank) s_bsel = tid;
  }
  // stage -2*v while the select settles
  if (tid >= 128) {
    int c = (tid - 128) * 4;
    vf4 t4 = *(const vf4*)&v[c];
    *(vf4*)&s_v[c] = t4 * -2.0f;
  }
  __syncthreads();
  const int b = __builtin_amdgcn_readfirstlane(s_bsel);
  const int len = lens[b];

  {  // stage Q rows for this t-tile
    int r = tid >> 6, c0 = (tid & 63) * 4;
#pragma unroll
    for (int u = 0; u < 2; ++u) {
      int c = c0 + u * 256;
      *(vf4*)&s_wsq[r][c] = *(const vf4*)&wsq[((size_t)b * T + tt * TT + r) * H + c];
    }
  }
  __syncthreads();

  // ---- Phase A: 64-s strips, wave w takes strips k=(w+tt) mod 4. Thread owns
  // one s for all 4 t; h processed in 8-elem planes, 2-plane pipeline. ----
  {
    const int wv = tid >> 6, lane = tid & 63;
    const int NS = (len + 63) >> 6;
    const float* e8b = e8 + (size_t)b * (H * S);
    for (int k = (wv + tt) & 3; k < NS; k += 4) {
      const int s = k * 64 + lane;
      const float* ep = e8b + (size_t)s * 8;  // plane stride S*8
      float ac0 = 0.f, ac1 = 0.f, ac2 = 0.f, ac3 = 0.f;
      // planes 0,1 preloaded; loop body: prefetch g*2+2, g*2+3, compute 2 planes
      vf4 cA0 = *(const vf4*)(ep);
      vf4 cA1 = *(const vf4*)(ep + 4);
      vf4 cB0 = *(const vf4*)(ep + (size_t)(S * 8));
      vf4 cB1 = *(const vf4*)(ep + (size_t)(S * 8) + 4);
      for (int g = 0; g < H / 16; ++g) {
        vf4 nA0, nA1, nB0, nB1;
        if (g + 1 < H / 16) {
          const float* np = ep + (size_t)(2 * g + 2) * (S * 8);
          nA0 = *(const vf4*)(np);
          nA1 = *(const vf4*)(np + 4);
          nB0 = *(const vf4*)(np + (size_t)(S * 8));
          nB1 = *(const vf4*)(np + (size_t)(S * 8) + 4);
        } else {
          nA0 = cA0; nA1 = cA1; nB0 = cB0; nB1 = cB1;
        }
        const int h = g * 16;
        plane8(ac0, &s_wsq[0][h], &s_v[h], cA0, cA1);
        plane8(ac1, &s_wsq[1][h], &s_v[h], cA0, cA1);
        plane8(ac2, &s_wsq[2][h], &s_v[h], cA0, cA1);
        plane8(ac3, &s_wsq[3][h], &s_v[h], cA0, cA1);
        plane8(ac0, &s_wsq[0][h + 8], &s_v[h + 8], cB0, cB1);
        plane8(ac1, &s_wsq[1][h + 8], &s_v[h + 8], cB0, cB1);
        plane8(ac2, &s_wsq[2][h + 8], &s_v[h + 8], cB0, cB1);
        plane8(ac3, &s_wsq[3][h + 8], &s_v[h + 8], cB0, cB1);
        cA0 = nA0; cA1 = nA1; cB0 = nB0; cB1 = nB1;
      }
      s_sc[0][s] = ac0; s_sc[1][s] = ac1; s_sc[2][s] = ac2; s_sc[3][s] = ac3;
    }
  }
  __syncthreads();

  // ---- Phase B: masked softmax; wave w handles row w ----
  {
    const int tr = tid >> 6, lane = tid & 63;
    float vals[S / 64], ps[S / 64];
    float m = -3.0e38f;
#pragma unroll
    for (int i = 0; i < S / 64; ++i) {
      int s = lane + 64 * i;
      vals[i] = s_sc[tr][s];
      if (s < len) m = fmaxf(m, vals[i]);
    }
#pragma unroll
    for (int o = 1; o < 64; o <<= 1) m = fmaxf(m, __shfl_xor(m, o, 64));
    float sum = 0.f;
#pragma unroll
    for (int i = 0; i < S / 64; ++i) {
      int s = lane + 64 * i;
      float p = (s < len) ? __builtin_amdgcn_exp2f((vals[i] - m) * 1.44269504088896341f) : 0.f;
      ps[i] = p;
      sum += p;
    }
#pragma unroll
    for (int o = 1; o < 64; o <<= 1) sum += __shfl_xor(sum, o, 64);
    float rs = 1.0f / sum;
#pragma unroll
    for (int i = 0; i < S / 64; ++i) s_sc[tr][lane + 64 * i] = ps[i];
    if (lane == 0) s_rs[tr] = rs;
    if (tt == T / TT - 1 && tr == TT - 1) {  // last timestep: attention weights
#pragma unroll
      for (int i = 0; i < S / 64; ++i)
        out[(size_t)B * T * H + (size_t)b * S + lane + 64 * i] = ps[i] * rs;
    }
  }
  __syncthreads();

  // ---- Phase C: ctx[t][h] = sum_{s<len} p[t][s] * enc[b][s][h]; wave = t ----
  {
    const int tg = tid >> 6, lane = tid & 63;
    const int h0 = lane * 4, h1 = 256 + lane * 4;
    float acc[8] = {};
    const float* encb = enc + (size_t)b * S * H;
    const int len4 = (len + 3) & ~3;  // p == 0 beyond len, safe to over-read
    for (int s0 = 0; s0 < len4; s0 += 4) {
      vf4 p4 = *(const vf4*)&s_sc[tg][s0];
#pragma unroll
      for (int k = 0; k < 4; ++k) {
        const float* er = encb + (size_t)(s0 + k) * H;
        float4 e0 = *(const float4*)(er + h0);
        float4 e1 = *(const float4*)(er + h1);
        float ev[8] = {e0.x, e0.y, e0.z, e0.w, e1.x, e1.y, e1.z, e1.w};
#pragma unroll
        for (int q = 0; q < 8; ++q) acc[q] = __builtin_fmaf(p4[k], ev[q], acc[q]);
      }
    }
    const float rs = s_rs[tg];
    const size_t base = ((size_t)b * T + tt * TT + tg) * H;
    float4 o;
    o = make_float4(acc[0] * rs, acc[1] * rs, acc[2] * rs, acc[3] * rs);
    *(float4*)&out[base + h0] = o;
    o = make_float4(acc[4] * rs, acc[5] * rs, acc[6] * rs, acc[7] * rs);
    *(float4*)&out[base + h1] = o;
  }
}

extern "C" void kernel_launch(void* const* d_in, const int* in_sizes, int n_in,
                              void* d_out, int out_size, void* d_ws, size_t ws_size,
                              hipStream_t stream) {
  const float* query = (const float*)d_in[0];  // [B,T,H]
  const float* enc   = (const float*)d_in[1];  // [B,S,H]
  const int*   lens  = (const int*)d_in[2];    // [B]
  const float* Ws    = (const float*)d_in[3];  // [H,H]
  const float* Wh    = (const float*)d_in[4];  // [H,H]
  const float* v     = (const float*)d_in[5];  // [H]
  float* out = (float*)d_out;
  float* wsq = (float*)d_ws;                   // [B,T,H] = Q
  float* e8  = wsq + (size_t)B * T * H;        // [B,H/8,S,8] = E

  matmul_nt_kernel<false><<<dim3((B * T / 64) * 8), 256, 0, stream>>>(query, Ws, wsq, C2LOG2E, nullptr);
  matmul_nt_kernel<true><<<dim3((B * S / 64) * 8), 256, 0, stream>>>(enc, Wh, e8, C2LOG2E, lens);
  attn_fused_kernel<<<dim3(B * (T / TT)), 256, 0, stream>>>(wsq, e8, enc, v, lens, out);
}